// Round 11
// baseline (104.537 us; speedup 1.0000x reference)
//
#include <hip/hip_runtime.h>
#include <hip/hip_bf16.h>
#include <math.h>

#define B_ 8
#define N_ 256
#define H_ 128
#define NODES_ (B_ * N_)   // 2048

__device__ __forceinline__ float silu_fast(float x) {
    float e = __expf(-x);
    return x * __builtin_amdgcn_rcpf(1.0f + e);
}

// ---------------------------------------------------------------------------
// k1 (split-K): g=0: P = node@We1a + be1
//               g=1: Q = node@We1b + (m_j-1)*1e30   (mask_j folded: silu -> -0)
//               g=2: pre = node@Wn1a + bn1
// grid 1536 = 3 gemms x 512 tiles (4 nodes), block 512.
// Each weight float4 loaded by exactly one thread (no L2 read amplification),
// reused across 4 nodes; 16-way k-segment reduce through LDS.  [R8: proven]
// ---------------------------------------------------------------------------
__global__ __launch_bounds__(512) void k1(
    const float* __restrict__ node, const float* __restrict__ We1,
    const float* __restrict__ be1, const float* __restrict__ Wn1,
    const float* __restrict__ bn1, const float* __restrict__ mask,
    float* __restrict__ P, float* __restrict__ Q, float* __restrict__ pre)
{
    __shared__ __align__(16) float act[4][128];
    __shared__ __align__(16) float pls[16][4][128];
    const int t = threadIdx.x;
    const int g = blockIdx.x >> 9;
    const int node0 = (blockIdx.x & 511) * 4;

    if (t < 128) {
        int r = t >> 5, col = (t & 31) * 4;
        *(float4*)(&act[r][col]) = *(const float4*)(node + (size_t)(node0 + r) * H_ + col);
    }
    const float* W = (g == 0) ? We1 : (g == 1) ? (We1 + 128 * H_) : Wn1;
    const int kseg = t >> 5;
    const int c0   = (t & 31) * 4;
    __syncthreads();

    float4 w[8];
    const float* Wb = W + (size_t)(kseg * 8) * H_ + c0;
    #pragma unroll
    for (int u = 0; u < 8; ++u) w[u] = *(const float4*)(Wb + u * H_);

    #pragma unroll
    for (int n = 0; n < 4; ++n) {
        float4 a = {0.f, 0.f, 0.f, 0.f};
        #pragma unroll
        for (int u = 0; u < 8; ++u) {
            float v = act[n][kseg * 8 + u];
            a.x = fmaf(v, w[u].x, a.x);
            a.y = fmaf(v, w[u].y, a.y);
            a.z = fmaf(v, w[u].z, a.z);
            a.w = fmaf(v, w[u].w, a.w);
        }
        *(float4*)(&pls[kseg][n][c0]) = a;
    }
    __syncthreads();

    {
        const int n = t >> 7;
        const int c = t & 127;
        float s = 0.f;
        #pragma unroll
        for (int seg = 0; seg < 16; ++seg) s += pls[seg][n][c];
        float* op;
        if (g == 0)      { op = P;   s += be1[c]; }
        else if (g == 1) { op = Q;   s += (mask[node0 + n] - 1.0f) * 1e30f; }
        else             { op = pre; s += bn1[c]; }
        op[(size_t)(node0 + n) * H_ + c] = s;
    }
}

// ---------------------------------------------------------------------------
// k2bc (R11): fused edge loop + node epilogue. grid 512 (4 i/block),
// block 512, __launch_bounds__(512, 4) [R10 spill guard].
// Edge: thread = (jq = t>>7 j-quarter, il = (t>>5)&3, cg = t&31, c0=cg*4);
// each thread owns 4 CHANNELS -> q consumed as ONE float4 per 4 evals,
// read DIRECTLY from L2 (Q[b]=128 KB L2-resident; dense-in-wave addresses,
// 2-way i-lane dedup). No LDS staging, no chunk barriers.
// R10 lesson (arithmetic): per-CU LDS pipe was the wall (~16 us of b32 q
// reads); trans pipe (2/eval, ~6.8 us/SIMD) is the intended floor.
// d read as b128 broadcast from dt[il][j] every 4 j. 4-way jq reduce in LDS.
// Epilogue: 3 chained split-K GEMMs (16 ksegs x 8 k)  [R10: proven].
// ---------------------------------------------------------------------------
__global__ __launch_bounds__(512, 4) void k2bc(
    const float* __restrict__ P, const float* __restrict__ Q,
    const float* __restrict__ We1, const float* __restrict__ positions,
    const float* __restrict__ mask, const float* __restrict__ pre,
    const float* __restrict__ node,
    const float* __restrict__ We2, const float* __restrict__ be2,
    const float* __restrict__ Wn1, const float* __restrict__ Wn2,
    const float* __restrict__ bn2, float* __restrict__ out)
{
    __shared__ __align__(16) float arena[8192];   // 32 KB: parts[4][4][128] | pls[16][4][128]
    __shared__ __align__(16) float dt[4][256];    // transposed dist [i][j]
    __shared__ float Sls[4][128];
    __shared__ float Tls[4][128];
    __shared__ float cs;
    const int t  = threadIdx.x;
    const int b  = blockIdx.x >> 6;
    const int i0 = (blockIdx.x & 63) * 4;

    // distances (transposed): thread (t&255) owns j; halves fill i-pairs
    {
        const int j    = t & 255;
        const int half = t >> 8;           // 0: il 0,1   1: il 2,3
        const float* pb = positions + b * N_ * 3;
        const float pjx = pb[j * 3 + 0];
        const float pjy = pb[j * 3 + 1];
        const float pjz = pb[j * 3 + 2];
        #pragma unroll
        for (int p = 0; p < 2; ++p) {
            const int il = half * 2 + p;
            float dx = pb[(i0 + il) * 3 + 0] - pjx;   // i-coords: uniform loads
            float dy = pb[(i0 + il) * 3 + 1] - pjy;
            float dz = pb[(i0 + il) * 3 + 2] - pjz;
            float sq = dx * dx + dy * dy + dz * dz;
            dt[il][j] = (sq > 0.f) ? sqrtf(sq) : 0.f;
        }
    }
    if (t < 64) {   // cnt = sum_j mask[b][j]
        float mv = mask[b * N_ + t] + mask[b * N_ + 64 + t]
                 + mask[b * N_ + 128 + t] + mask[b * N_ + 192 + t];
        #pragma unroll
        for (int off = 32; off >= 1; off >>= 1) mv += __shfl_down(mv, off);
        if (t == 0) cs = mv;
    }
    __syncthreads();                  // dt + cs visible

    // ---- edge loop: direct-L2 float4 q reads, 4 channels/thread ----
    const int jq = t >> 7;            // wave-pair uniform, 0..3
    const int il = (t >> 5) & 3;
    const int c0 = (t & 31) * 4;
    float4 base4 = *(const float4*)(P + (size_t)(b * N_ + i0 + il) * H_ + c0);
    float4 wd4   = *(const float4*)(We1 + (size_t)(256) * H_ + c0);
    const float* __restrict__ Qb = Q + (size_t)(b * N_ + jq * 64) * H_ + c0;

    float4 acc = {0.f, 0.f, 0.f, 0.f};
    #pragma unroll 4
    for (int jw = 0; jw < 16; ++jw) {
        float4 d4 = *(const float4*)(&dt[il][jq * 64 + jw * 4]);   // b128 broadcast
        #pragma unroll
        for (int u = 0; u < 4; ++u) {
            float4 q4 = *(const float4*)(Qb + (size_t)(jw * 4 + u) * H_);
            float d = (u == 0) ? d4.x : (u == 1) ? d4.y : (u == 2) ? d4.z : d4.w;
            float x0 = fmaf(d, wd4.x, base4.x + q4.x);
            float x1 = fmaf(d, wd4.y, base4.y + q4.y);
            float x2 = fmaf(d, wd4.z, base4.z + q4.z);
            float x3 = fmaf(d, wd4.w, base4.w + q4.w);
            float r0 = __builtin_amdgcn_rcpf(1.0f + __expf(-x0));
            float r1 = __builtin_amdgcn_rcpf(1.0f + __expf(-x1));
            float r2 = __builtin_amdgcn_rcpf(1.0f + __expf(-x2));
            float r3 = __builtin_amdgcn_rcpf(1.0f + __expf(-x3));
            acc.x = fmaf(x0, r0, acc.x);   // masked j: x~-1e30, r=0 -> +(-0)
            acc.y = fmaf(x1, r1, acc.y);
            acc.z = fmaf(x2, r2, acc.z);
            acc.w = fmaf(x3, r3, acc.w);
        }
    }

    // 4-way jq reduce through LDS
    float (*parts)[4][128] = (float (*)[4][128])arena;
    *(float4*)(&parts[jq][il][c0]) = acc;
    __syncthreads();
    const int i = t >> 7;             // reduce/epilogue row, 0..3 (wave-uniform)
    const int c = t & 127;
    const float inv_cnt = __builtin_amdgcn_rcpf(fmaxf(cs, 1.0f));
    const float mi = mask[b * N_ + i0 + i];
    {
        float s = (parts[0][i][c] + parts[1][i][c])
                + (parts[2][i][c] + parts[3][i][c]);
        Sls[i][c] = (mi * inv_cnt) * s;
    }
    __syncthreads();                  // Sls visible; arena free for pls

    // ---- epilogue: split-K GEMMs (16 ksegs x 8 k)  [R10 verbatim] ----
    float (*pls)[4][128] = (float (*)[4][128])arena;
    const int kseg = t >> 5;          // 0..15

    // G1: T = S' @ We2 + mi*be2
    {
        const float* Wb = We2 + (size_t)(kseg * 8) * H_ + c0;
        float4 w[8];
        #pragma unroll
        for (int u = 0; u < 8; ++u) w[u] = *(const float4*)(Wb + u * H_);
        #pragma unroll
        for (int n = 0; n < 4; ++n) {
            float4 a = {0.f, 0.f, 0.f, 0.f};
            #pragma unroll
            for (int u = 0; u < 8; ++u) {
                float v = Sls[n][kseg * 8 + u];
                a.x = fmaf(v, w[u].x, a.x); a.y = fmaf(v, w[u].y, a.y);
                a.z = fmaf(v, w[u].z, a.z); a.w = fmaf(v, w[u].w, a.w);
            }
            *(float4*)(&pls[kseg][n][c0]) = a;
        }
    }
    __syncthreads();
    {
        float s = 0.f;
        #pragma unroll
        for (int seg = 0; seg < 16; ++seg) s += pls[seg][i][c];
        Tls[i][c] = fmaf(mi, be2[c], s);
    }
    __syncthreads();

    // G2: hidden = silu(pre + T @ Wn1[128:])
    {
        const float* Wb = Wn1 + (size_t)(128 + kseg * 8) * H_ + c0;
        float4 w[8];
        #pragma unroll
        for (int u = 0; u < 8; ++u) w[u] = *(const float4*)(Wb + u * H_);
        #pragma unroll
        for (int n = 0; n < 4; ++n) {
            float4 a = {0.f, 0.f, 0.f, 0.f};
            #pragma unroll
            for (int u = 0; u < 8; ++u) {
                float v = Tls[n][kseg * 8 + u];
                a.x = fmaf(v, w[u].x, a.x); a.y = fmaf(v, w[u].y, a.y);
                a.z = fmaf(v, w[u].z, a.z); a.w = fmaf(v, w[u].w, a.w);
            }
            *(float4*)(&pls[kseg][n][c0]) = a;
        }
    }
    __syncthreads();
    {
        float s = 0.f;
        #pragma unroll
        for (int seg = 0; seg < 16; ++seg) s += pls[seg][i][c];
        Sls[i][c] = silu_fast(pre[(size_t)(b * N_ + i0 + i) * H_ + c] + s);
    }
    __syncthreads();

    // G3: out = node + mi * (hidden @ Wn2 + bn2)
    {
        const float* Wb = Wn2 + (size_t)(kseg * 8) * H_ + c0;
        float4 w[8];
        #pragma unroll
        for (int u = 0; u < 8; ++u) w[u] = *(const float4*)(Wb + u * H_);
        #pragma unroll
        for (int n = 0; n < 4; ++n) {
            float4 a = {0.f, 0.f, 0.f, 0.f};
            #pragma unroll
            for (int u = 0; u < 8; ++u) {
                float v = Sls[n][kseg * 8 + u];
                a.x = fmaf(v, w[u].x, a.x); a.y = fmaf(v, w[u].y, a.y);
                a.z = fmaf(v, w[u].z, a.z); a.w = fmaf(v, w[u].w, a.w);
            }
            *(float4*)(&pls[kseg][n][c0]) = a;
        }
    }
    __syncthreads();
    {
        float s = 0.f;
        #pragma unroll
        for (int seg = 0; seg < 16; ++seg) s += pls[seg][i][c];
        const size_t idx = (size_t)(b * N_ + i0 + i) * H_ + c;
        out[idx] = node[idx] + mi * (s + bn2[c]);
    }
}

extern "C" void kernel_launch(void* const* d_in, const int* in_sizes, int n_in,
                              void* d_out, int out_size, void* d_ws, size_t ws_size,
                              hipStream_t stream)
{
    const float* node      = (const float*)d_in[0];
    const float* positions = (const float*)d_in[1];
    const float* mask      = (const float*)d_in[2];
    const float* We1       = (const float*)d_in[3];
    const float* be1       = (const float*)d_in[4];
    const float* We2       = (const float*)d_in[5];
    const float* be2       = (const float*)d_in[6];
    const float* Wn1       = (const float*)d_in[7];
    const float* bn1       = (const float*)d_in[8];
    const float* Wn2       = (const float*)d_in[9];
    const float* bn2       = (const float*)d_in[10];
    float* out = (float*)d_out;

    const size_t SZ = (size_t)NODES_ * H_;     // 1 MB each
    float* P   = (float*)d_ws;
    float* Q   = P + SZ;
    float* pre = Q + SZ;                       // peak ws = 3 MB

    k1  <<<1536, 512, 0, stream>>>(node, We1, be1, Wn1, bn1, mask, P, Q, pre);
    k2bc<<<512,  512, 0, stream>>>(P, Q, We1, positions, mask, pre, node,
                                   We2, be2, Wn1, Wn2, bn2, out);
}